// Round 8
// baseline (2233.462 us; speedup 1.0000x reference)
//
#include <hip/hip_runtime.h>

// OT_GNN_layer — round 8: corrected constants, hardcoded sizes.
// GROUND TRUTH from reference listing: N,F,T,Tn,C = 10000,128,16,8,8  (T=16!)
// E = N*K = 160000, edge_index planar [2,E] int32 (verified by probe R7:
// d_in[1] first 160000 words == e>>4 == src row). dst = edge + 160000.
// in_sizes/n_in are NOT trusted (probe R6/R7 proved they don't carry flat
// element counts) — everything hardcoded.
//
// Dumb-but-faithful transliteration (R4 pipeline, proven self-consistent):
// one thread per (node i, template t): 160000 threads. Per-thread 17x8 plan
// in scratch. Linear head [16 templates -> 8 classes] via LDS exchange.

#define F_DIM 128
#define KN 16
#define NL 17    // star subgraph: center + 16 neighbors
#define TT 16    // n_templates  (T = 16 !)
#define TN 8     // template size
#define NC 8     // n_classes
#define N_NODES 10000
#define E_EDGES 160000

__global__ __launch_bounds__(256) void fgw_dumb16_kernel(
    const float* __restrict__ x, const int* __restrict__ edge,
    const float* __restrict__ L, const float* __restrict__ TF,
    const float* __restrict__ W, const float* __restrict__ bias,
    float* __restrict__ out) {
  const int tid = threadIdx.x;
  const int gid = blockIdx.x * 256 + tid;   // < 160000 always (625 blocks)
  const int i = gid >> 4;   // node
  const int t = gid & 15;   // template
  const int* dst = edge + E_EDGES;

  // neighbor list (row 0 = the node itself); defensive clamp
  int na[NL];
  na[0] = i;
  for (int j = 0; j < KN; ++j) {
    int nb = dst[i * KN + j];
    na[1 + j] = (nb >= 0 && nb < N_NODES) ? nb : 0;
  }

  // C2 = 0.5*(L_t + L_t^T); cc[m] = (1/8) sum_j C2[m][j]^2
  float C2[TN][TN], cc[TN];
  for (int l = 0; l < TN; ++l)
    for (int m = 0; m < TN; ++m)
      C2[l][m] = 0.5f * (L[t * 64 + l * 8 + m] + L[t * 64 + m * 8 + l]);
  for (int m = 0; m < TN; ++m) {
    float q = 0.f;
    for (int j = 0; j < TN; ++j) q += C2[m][j] * C2[m][j];
    cc[m] = 0.125f * q;
  }

  // tfsq[m] = |TF[t][m][:]|^2
  float tfsq[TN];
  for (int m = 0; m < TN; ++m) {
    const float4* tf = (const float4*)(TF + (size_t)(t * 8 + m) * F_DIM);
    float s = 0.f;
    for (int c = 0; c < 32; ++c) {
      float4 v = tf[c];
      s += v.x * v.x + v.y * v.y + v.z * v.z + v.w * v.w;
    }
    tfsq[m] = s;
  }

  // M[a][m] = (|x_na|^2 + |TF[t][m]|^2 - 2 x_na.TF[t][m]) / F
  float M[NL][TN];
  for (int a = 0; a < NL; ++a) {
    const float4* xr = (const float4*)(x + (size_t)na[a] * F_DIM);
    float xsq = 0.f;
    float dot[TN];
    for (int m = 0; m < TN; ++m) dot[m] = 0.f;
    for (int c = 0; c < 32; ++c) {
      float4 xv = xr[c];
      xsq += xv.x * xv.x + xv.y * xv.y + xv.z * xv.z + xv.w * xv.w;
      for (int m = 0; m < TN; ++m) {
        float4 tv = ((const float4*)(TF + (size_t)(t * 8 + m) * F_DIM))[c];
        dot[m] += xv.x * tv.x + xv.y * tv.y + xv.z * tv.z + xv.w * tv.w;
      }
    }
    for (int m = 0; m < TN; ++m)
      M[a][m] = (xsq + tfsq[m] - 2.f * dot[m]) * (1.f / (float)F_DIM);
  }

  // ---- FGW proximal + Sinkhorn (faithful transliteration) ----
  float P[NL][TN], Km[NL][TN];
  for (int a = 0; a < NL; ++a)
    for (int m = 0; m < TN; ++m) P[a][m] = (1.f / 17.f) * 0.125f;

  float A0[TN], A1[TN];  // A row 0 ; A rows >=1 (all equal, star C1)
#pragma unroll 1
  for (int it = 0; it < 5; ++it) {
    float rs[TN];
    for (int l = 0; l < TN; ++l) {
      float s = 0.f;
      for (int k = 1; k < NL; ++k) s += P[k][l];
      rs[l] = s;
    }
    for (int m = 0; m < TN; ++m) {
      float s0 = 0.f, s1 = 0.f;
      for (int l = 0; l < TN; ++l) {
        s0 += rs[l] * C2[l][m];
        s1 += P[0][l] * C2[l][m];
      }
      A0[m] = s0;
      A1[m] = s1;
    }
    float gmin = 1e30f;
    for (int a = 0; a < NL; ++a) {
      float cr = (a == 0) ? (16.f / 17.f) : (1.f / 17.f);
      for (int m = 0; m < TN; ++m) {
        float g = 0.5f * (M[a][m] + cr + cc[m]) - ((a == 0) ? A0[m] : A1[m]);
        Km[a][m] = g;
        gmin = fminf(gmin, g);
      }
    }
    for (int a = 0; a < NL; ++a)
      for (int m = 0; m < TN; ++m)
        Km[a][m] = P[a][m] * expf(-(Km[a][m] - gmin) * 5.f);  // 1/EPS = 5

    float u[NL], v[TN];
    for (int m = 0; m < TN; ++m) v[m] = 1.f;
#pragma unroll 1
    for (int si = 0; si < 10; ++si) {
      for (int a = 0; a < NL; ++a) {
        float s = 0.f;
        for (int m = 0; m < TN; ++m) s += Km[a][m] * v[m];
        u[a] = (1.f / 17.f) / (s + 1e-30f);
      }
      for (int m = 0; m < TN; ++m) {
        float s = 0.f;
        for (int a = 0; a < NL; ++a) s += Km[a][m] * u[a];
        v[m] = 0.125f / (s + 1e-30f);
      }
    }
    for (int a = 0; a < NL; ++a)
      for (int m = 0; m < TN; ++m) P[a][m] = u[a] * Km[a][m] * v[m];
  }

  // final fgw(i,t)
  float fgw_val;
  {
    float rs[TN];
    for (int l = 0; l < TN; ++l) {
      float s = 0.f;
      for (int k = 1; k < NL; ++k) s += P[k][l];
      rs[l] = s;
    }
    for (int m = 0; m < TN; ++m) {
      float s0 = 0.f, s1 = 0.f;
      for (int l = 0; l < TN; ++l) {
        s0 += rs[l] * C2[l][m];
        s1 += P[0][l] * C2[l][m];
      }
      A0[m] = s0;
      A1[m] = s1;
    }
    float s = 0.f;
    for (int a = 0; a < NL; ++a) {
      float cr = (a == 0) ? (16.f / 17.f) : (1.f / 17.f);
      for (int m = 0; m < TN; ++m) {
        float g = 0.5f * (M[a][m] + cr + cc[m]) - ((a == 0) ? A0[m] : A1[m]);
        s += g * P[a][m];
      }
    }
    fgw_val = s;
  }

  // ---- head: out[i][c] = b[c] + sum_{t<16} fgw[i,t] W[t*8+c] ----
  __shared__ float fgw_s[256];
  fgw_s[tid] = fgw_val;   // [i_loc=tid>>4][t=tid&15]
  __syncthreads();
  const int i_loc = tid >> 4, c = tid & 15;
  if (c < NC) {
    const int i_out = blockIdx.x * 16 + i_loc;
    float o = bias[c];
    for (int t2 = 0; t2 < TT; ++t2)
      o += fgw_s[i_loc * 16 + t2] * W[t2 * 8 + c];
    out[i_out * 8 + c] = o;
  }
}

extern "C" void kernel_launch(void* const* d_in, const int* in_sizes, int n_in,
                              void* d_out, int out_size, void* d_ws, size_t ws_size,
                              hipStream_t stream) {
  const float* x = (const float*)d_in[0];
  const int* edge = (const int*)d_in[1];
  const float* L = (const float*)d_in[2];
  const float* TF = (const float*)d_in[3];
  const float* W = (const float*)d_in[4];
  const float* bias = (const float*)d_in[5];
  float* out = (float*)d_out;
  (void)in_sizes; (void)n_in; (void)d_ws; (void)ws_size; (void)out_size;

  // N*T = 160000 threads, 625 blocks of 256 (16 nodes x 16 templates each)
  fgw_dumb16_kernel<<<(N_NODES * TT) / 256, 256, 0, stream>>>(x, edge, L, TF,
                                                              W, bias, out);
}

// Round 9
// 751.432 us; speedup vs baseline: 2.9723x; 2.9723x over previous
//
#include <hip/hip_runtime.h>

// OT_GNN_layer — round 9: wave-parallel FGW with CORRECT constants.
// N,F,T,Tn,C = 10000,128,16,8,8 ; E=160000 ; edge planar [2,E]; all hardcoded
// (in_sizes untrusted — probes R6/R7). Validated math = R8 transliteration.
//
// One wave per (node, template-half of 8): lane = (t=lane>>3, m=lane&7) owns
// column m of the 17x8 plan for template toff+t, entirely in registers.
// Block 256 = 4 waves = 2 nodes (waves 2w,2w+1 -> node_loc w, toff 0/8).
// Row sums over m: __shfl_xor(1,2,4) in the 8-lane group; column sums
// lane-local. Head [16->8] via tiny LDS exchange.

#define F_DIM 128
#define KN 16
#define NL 17
#define TT 16
#define TN 8
#define NC 8
#define N_NODES 10000
#define E_EDGES 160000
#define TINY 1e-30f

__device__ __forceinline__ float group8_sum(float x) {
  x += __shfl_xor(x, 1, 64);
  x += __shfl_xor(x, 2, 64);
  x += __shfl_xor(x, 4, 64);
  return x;
}
__device__ __forceinline__ float group8_min(float x) {
  x = fminf(x, __shfl_xor(x, 1, 64));
  x = fminf(x, __shfl_xor(x, 2, 64));
  x = fminf(x, __shfl_xor(x, 4, 64));
  return x;
}

__global__ __launch_bounds__(256) void fgw_wave_kernel(
    const float* __restrict__ x, const int* __restrict__ edge,
    const float* __restrict__ L, const float* __restrict__ TF,
    const float* __restrict__ W, const float* __restrict__ bias,
    float* __restrict__ out) {
  __shared__ float C2s[TT][TN][TN];  // C2[t][l][m]
  __shared__ float ccs[TT * TN];     // cc[t][m] = (1/8) sum_l C2[t][m][l]^2
  __shared__ float tfsqs[TT * TN];   // |TF row|^2
  __shared__ float fgw_s[2][TT];     // per-block: 2 nodes x 16 templates

  const int tid = threadIdx.x;

  // ---- preamble: C2 / cc (threads 0..127), tfsq (threads 128..255) ----
  if (tid < 128) {
    const int t = tid >> 3, r = tid & 7;
    float q = 0.f;
#pragma unroll
    for (int mm = 0; mm < TN; ++mm) {
      float val = 0.5f * (L[t * 64 + r * 8 + mm] + L[t * 64 + mm * 8 + r]);
      C2s[t][r][mm] = val;
      q += val * val;
    }
    ccs[tid] = 0.125f * q;
  } else {
    const int row = tid - 128;  // 0..127 = t*8+m
    const float4* tf = (const float4*)(TF + (size_t)row * F_DIM);
    float s = 0.f;
#pragma unroll
    for (int c = 0; c < 32; ++c) {
      float4 v = tf[c];
      s += v.x * v.x + v.y * v.y + v.z * v.z + v.w * v.w;
    }
    tfsqs[row] = s;
  }
  __syncthreads();

  const int lane = tid & 63;
  const int wave = tid >> 6;          // 0..3
  const int node_loc = wave >> 1;     // 0,1
  const int toff = (wave & 1) * 8;    // template half
  const int node = blockIdx.x * 2 + node_loc;
  const int tl = lane >> 3, m = lane & 7;
  const int tg = toff + tl;           // global template id

  // ---- neighbor list (wave-uniform broadcast loads) ----
  const int* dst = edge + E_EDGES;
  int na[NL];
  na[0] = node;
#pragma unroll
  for (int j = 0; j < KN; ++j) na[1 + j] = dst[node * KN + j];

  // ---- dot phase: macc[a] = sum_f x*(x - 2*TF_lane) ----
  float macc[NL];
#pragma unroll
  for (int a = 0; a < NL; ++a) macc[a] = 0.f;

  const float4* TFrow = (const float4*)(TF + (size_t)(tg * 8 + m) * F_DIM);
#pragma unroll 4
  for (int c = 0; c < 32; ++c) {
    float4 tf = TFrow[c];
    float t2x = -2.f * tf.x, t2y = -2.f * tf.y, t2z = -2.f * tf.z,
          t2w = -2.f * tf.w;
#pragma unroll
    for (int a = 0; a < NL; ++a) {
      float4 xv = *(const float4*)(x + (size_t)na[a] * F_DIM + c * 4);
      float acc = macc[a];
      acc = fmaf(xv.x, xv.x + t2x, acc);
      acc = fmaf(xv.y, xv.y + t2y, acc);
      acc = fmaf(xv.z, xv.z + t2z, acc);
      acc = fmaf(xv.w, xv.w + t2w, acc);
      macc[a] = acc;
    }
  }

  const float tfsq_l = tfsqs[tg * 8 + m];
  float M[NL];
#pragma unroll
  for (int a = 0; a < NL; ++a)
    M[a] = (macc[a] + tfsq_l) * (1.f / (float)F_DIM);

  // ---- FGW proximal + Sinkhorn ----
  const float hw = 1.f / 17.f;
  const float pw = 0.125f;
  const float cr0 = 16.f / 17.f;
  const float cra = 1.f / 17.f;

  float C2col[TN];
#pragma unroll
  for (int l = 0; l < TN; ++l) C2col[l] = C2s[tg][l][m];
  const float cc_l = ccs[tg * 8 + m];

  float P[NL], Kc[NL], u[NL];
#pragma unroll
  for (int a = 0; a < NL; ++a) P[a] = hw * pw;

  float A0 = 0.f, A1 = 0.f;
#pragma unroll 1
  for (int it = 0; it < 5; ++it) {
    float sP = 0.f;
#pragma unroll
    for (int a = 1; a < NL; ++a) sP += P[a];
    float p0 = P[0];
    A0 = 0.f;
    A1 = 0.f;
#pragma unroll
    for (int l = 0; l < TN; ++l) {
      int src = (lane & 56) | l;
      A0 += __shfl(sP, src, 64) * C2col[l];
      A1 += __shfl(p0, src, 64) * C2col[l];
    }
    float gmin = 1e30f;
#pragma unroll
    for (int a = 0; a < NL; ++a) {
      float gr = 0.5f * (M[a] + ((a == 0) ? cr0 : cra) + cc_l) -
                 ((a == 0) ? A0 : A1);
      Kc[a] = gr;
      gmin = fminf(gmin, gr);
    }
    gmin = group8_min(gmin);
    // K = P * exp(-(g-gmin)/EPS);  (1/EPS)*log2e = 7.2134752
#pragma unroll
    for (int a = 0; a < NL; ++a)
      Kc[a] = P[a] * exp2f((gmin - Kc[a]) * 7.2134752044448170f);

    float v = 1.f;
#pragma unroll 1
    for (int si = 0; si < 10; ++si) {
#pragma unroll
      for (int a = 0; a < NL; ++a) {
        float r = group8_sum(Kc[a] * v);
        u[a] = hw * __builtin_amdgcn_rcpf(r + TINY);
      }
      float r2 = TINY;
#pragma unroll
      for (int a = 0; a < NL; ++a) r2 = fmaf(Kc[a], u[a], r2);
      v = pw * __builtin_amdgcn_rcpf(r2);
    }
#pragma unroll
    for (int a = 0; a < NL; ++a) P[a] = u[a] * Kc[a] * v;
  }

  // ---- final fgw ----
  float sP = 0.f;
#pragma unroll
  for (int a = 1; a < NL; ++a) sP += P[a];
  float p0 = P[0];
  A0 = 0.f;
  A1 = 0.f;
#pragma unroll
  for (int l = 0; l < TN; ++l) {
    int src = (lane & 56) | l;
    A0 += __shfl(sP, src, 64) * C2col[l];
    A1 += __shfl(p0, src, 64) * C2col[l];
  }
  float acc = 0.f;
#pragma unroll
  for (int a = 0; a < NL; ++a) {
    float gr = 0.5f * (M[a] + ((a == 0) ? cr0 : cra) + cc_l) -
               ((a == 0) ? A0 : A1);
    acc += gr * P[a];
  }
  acc = group8_sum(acc);  // fgw(node, tg), replicated over the 8 group lanes

  if (m == 0) fgw_s[node_loc][tg] = acc;
  __syncthreads();

  // ---- head: out[i][c] = b[c] + sum_t fgw[i,t] W[t*8+c] ----
  if (tid < 16) {
    const int nl2 = tid >> 3, c = tid & 7;
    const int i_out = blockIdx.x * 2 + nl2;
    float o = bias[c];
#pragma unroll
    for (int t2 = 0; t2 < TT; ++t2) o += fgw_s[nl2][t2] * W[t2 * 8 + c];
    out[i_out * 8 + c] = o;
  }
}

extern "C" void kernel_launch(void* const* d_in, const int* in_sizes, int n_in,
                              void* d_out, int out_size, void* d_ws, size_t ws_size,
                              hipStream_t stream) {
  const float* x = (const float*)d_in[0];
  const int* edge = (const int*)d_in[1];
  const float* L = (const float*)d_in[2];
  const float* TF = (const float*)d_in[3];
  const float* W = (const float*)d_in[4];
  const float* bias = (const float*)d_in[5];
  float* out = (float*)d_out;
  (void)in_sizes; (void)n_in; (void)d_ws; (void)ws_size; (void)out_size;

  // 2 nodes per block -> 5000 blocks
  fgw_wave_kernel<<<N_NODES / 2, 256, 0, stream>>>(x, edge, L, TF, W, bias,
                                                   out);
}

// Round 10
// 745.904 us; speedup vs baseline: 2.9943x; 1.0074x over previous
//
#include <hip/hip_runtime.h>

// OT_GNN_layer — round 10: DPP butterflies + LDS A-exchange + packed-f32 dots.
// N,F,T,Tn,C = 10000,128,16,8,8 ; E=160000 ; edge planar [2,E]; hardcoded.
// Math validated by R8/R9 (absmax 4.9e-4).
//
// One wave per (node, template-half): lane=(t=lane>>3, m=lane&7) owns column m
// of the 17x8 plan for template toff+t in registers. Changes vs R9:
//  - 8-lane row reductions via DPP (quad_perm xor1=0xB1, xor2=0x4E,
//    row_half_mirror=0x141) -> VALU pipe, no ds_bpermute (R9: 1.12M LDS
//    bank conflicts, DS-pipe serialization capped VALUBusy at 60%).
//  - A-phase (C1 P C2) via per-wave LDS float2 exchange: 1 ds_write_b64 +
//    4 ds_read_b128 (group-broadcast, conflict-free) + 16 fma.
//  - dot phase: |x|^2 split out (lanes 0..16 compute, uniform-shfl bcast);
//    remaining dots are pure v_pk_fma_f32 (2 per float4-chunk per row).
//  - Mh = 0.5*(M+constC) precomputed; marginals folded out of inner loop.

#define F_DIM 128
#define KN 16
#define NL 17
#define TT 16
#define NC 8
#define TN 8
#define N_NODES 10000
#define E_EDGES 160000
#define TINY 1e-30f

typedef float v2f __attribute__((ext_vector_type(2)));

template <int CTRL>
__device__ __forceinline__ float dppmov(float x) {
  return __int_as_float(__builtin_amdgcn_update_dpp(
      0, __float_as_int(x), CTRL, 0xF, 0xF, true));
}
__device__ __forceinline__ float g8sum(float x) {
  x += dppmov<0xB1>(x);   // quad_perm [1,0,3,2] : xor 1
  x += dppmov<0x4E>(x);   // quad_perm [2,3,0,1] : xor 2
  x += dppmov<0x141>(x);  // row_half_mirror     : xor 4 within 8-lane half
  return x;
}
__device__ __forceinline__ float g8min(float x) {
  x = fminf(x, dppmov<0xB1>(x));
  x = fminf(x, dppmov<0x4E>(x));
  x = fminf(x, dppmov<0x141>(x));
  return x;
}

__global__ __launch_bounds__(256) void fgw_dpp_kernel(
    const float* __restrict__ x, const int* __restrict__ edge,
    const float* __restrict__ L, const float* __restrict__ TF,
    const float* __restrict__ W, const float* __restrict__ bias,
    float* __restrict__ out) {
  __shared__ float C2s[TT][TN][TN];
  __shared__ float ccs[TT * TN];
  __shared__ float tfsqs[TT * TN];
  __shared__ float2 sc[4][64];     // per-wave A-phase exchange (sP, p0)
  __shared__ float fgw_s[2][TT];

  const int tid = threadIdx.x;

  // ---- preamble ----
  if (tid < 128) {
    const int t = tid >> 3, r = tid & 7;
    float q = 0.f;
#pragma unroll
    for (int mm = 0; mm < TN; ++mm) {
      float val = 0.5f * (L[t * 64 + r * 8 + mm] + L[t * 64 + mm * 8 + r]);
      C2s[t][r][mm] = val;
      q += val * val;
    }
    ccs[tid] = 0.125f * q;
  } else {
    const int row = tid - 128;
    const float4* tf = (const float4*)(TF + (size_t)row * F_DIM);
    float s = 0.f;
#pragma unroll
    for (int c = 0; c < 32; ++c) {
      float4 v = tf[c];
      s += v.x * v.x + v.y * v.y + v.z * v.z + v.w * v.w;
    }
    tfsqs[row] = s;
  }
  __syncthreads();

  const int lane = tid & 63;
  const int wave = tid >> 6;
  const int node_loc = wave >> 1;
  const int toff = (wave & 1) * 8;
  const int node = blockIdx.x * 2 + node_loc;
  const int tl = lane >> 3, m = lane & 7;
  const int tg = toff + tl;

  const int* dst = edge + E_EDGES;
  int na[NL];
  na[0] = node;
#pragma unroll
  for (int j = 0; j < KN; ++j) na[1 + j] = dst[node * KN + j];

  // ---- xsq: lanes 0..16 each compute |x_row|^2 for one local row ----
  float xq_h = 0.f;
  if (lane < NL) {
    const int my_row = (lane == 0) ? node : dst[node * KN + (lane - 1)];
    const float4* xr = (const float4*)(x + (size_t)my_row * F_DIM);
    v2f xq = {0.f, 0.f};
#pragma unroll
    for (int c = 0; c < 32; ++c) {
      float4 xv = xr[c];
      v2f xa = {xv.x, xv.y}, xb = {xv.z, xv.w};
      xq = xa * xa + xq;
      xq = xb * xb + xq;
    }
    xq_h = xq.x + xq.y;
  }

  // ---- dot phase: dot2[a] = sum x . TF_lane  (v_pk_fma_f32) ----
  v2f dot2[NL];
#pragma unroll
  for (int a = 0; a < NL; ++a) dot2[a] = (v2f){0.f, 0.f};

  const float4* TFrow = (const float4*)(TF + (size_t)(tg * 8 + m) * F_DIM);
#pragma unroll 4
  for (int c = 0; c < 32; ++c) {
    float4 tf = TFrow[c];
    v2f ta = {tf.x, tf.y}, tb = {tf.z, tf.w};
#pragma unroll
    for (int a = 0; a < NL; ++a) {
      float4 xv = *(const float4*)(x + (size_t)na[a] * F_DIM + c * 4);
      v2f xa = {xv.x, xv.y}, xb = {xv.z, xv.w};
      dot2[a] = xa * ta + dot2[a];
      dot2[a] = xb * tb + dot2[a];
    }
  }

  // ---- Mh[a] = 0.5*(M[a] + constC_row + cc)  (outer-invariant) ----
  const float hw = 1.f / 17.f;
  const float pw = 0.125f;
  const float tfsq_l = tfsqs[tg * 8 + m];
  const float cc_l = ccs[tg * 8 + m];
  const float base0 = 0.5f * (16.f / 17.f + cc_l);
  const float basea = 0.5f * (1.f / 17.f + cc_l);

  float Mh[NL];
#pragma unroll
  for (int a = 0; a < NL; ++a) {
    float xsqa = __shfl(xq_h, a, 64);  // uniform src -> readlane broadcast
    float dh = dot2[a].x + dot2[a].y;
    Mh[a] = (xsqa + tfsq_l - 2.f * dh) * (1.f / 256.f) +
            ((a == 0) ? base0 : basea);
  }

  float C2col[TN];
#pragma unroll
  for (int l = 0; l < TN; ++l) C2col[l] = C2s[tg][l][m];

  float P[NL], Kc[NL], U[NL];
#pragma unroll
  for (int a = 0; a < NL; ++a) P[a] = hw * pw;

  float A0 = 0.f, A1 = 0.f;
#pragma unroll 1
  for (int it = 0; it < 5; ++it) {
    // ---- A = C1 P C2 via LDS exchange of (sP, p0) ----
    float sP = 0.f;
#pragma unroll
    for (int a = 1; a < NL; ++a) sP += P[a];
    sc[wave][lane] = make_float2(sP, P[0]);
    const float4* q = (const float4*)&sc[wave][tl * 8];
    float4 q0 = q[0], q1 = q[1], q2 = q[2], q3 = q[3];
    A0 = q0.x * C2col[0] + q0.z * C2col[1] + q1.x * C2col[2] +
         q1.z * C2col[3] + q2.x * C2col[4] + q2.z * C2col[5] +
         q3.x * C2col[6] + q3.z * C2col[7];
    A1 = q0.y * C2col[0] + q0.w * C2col[1] + q1.y * C2col[2] +
         q1.w * C2col[3] + q2.y * C2col[4] + q2.w * C2col[5] +
         q3.y * C2col[6] + q3.w * C2col[7];

    // ---- grad, min-stabilize, K = P*exp(-(g-gmin)/EPS) ----
    float gmin = 1e30f;
#pragma unroll
    for (int a = 0; a < NL; ++a) {
      float gr = Mh[a] - ((a == 0) ? A0 : A1);
      Kc[a] = gr;
      gmin = fminf(gmin, gr);
    }
    gmin = g8min(gmin);
#pragma unroll
    for (int a = 0; a < NL; ++a)
      Kc[a] = P[a] * exp2f((gmin - Kc[a]) * 7.2134752044448170f);

    // ---- Sinkhorn (marginals folded: U = u/h, vscale = p/h = 17/8) ----
    float vv = 1.f;
#pragma unroll 1
    for (int si = 0; si < 10; ++si) {
#pragma unroll
      for (int a = 0; a < NL; ++a) {
        float r = g8sum(Kc[a] * vv);
        U[a] = __builtin_amdgcn_rcpf(r + TINY);
      }
      float r2a = TINY, r2b = 0.f;
#pragma unroll
      for (int a = 0; a < 8; ++a) r2a = fmaf(Kc[a], U[a], r2a);
#pragma unroll
      for (int a = 8; a < NL; ++a) r2b = fmaf(Kc[a], U[a], r2b);
      vv = 2.125f * __builtin_amdgcn_rcpf(r2a + r2b);
    }
    const float pv = hw * vv;
#pragma unroll
    for (int a = 0; a < NL; ++a) P[a] = U[a] * Kc[a] * pv;
  }

  // ---- final fgw ----
  float sP = 0.f;
#pragma unroll
  for (int a = 1; a < NL; ++a) sP += P[a];
  sc[wave][lane] = make_float2(sP, P[0]);
  const float4* q = (const float4*)&sc[wave][tl * 8];
  float4 q0 = q[0], q1 = q[1], q2 = q[2], q3 = q[3];
  A0 = q0.x * C2col[0] + q0.z * C2col[1] + q1.x * C2col[2] + q1.z * C2col[3] +
       q2.x * C2col[4] + q2.z * C2col[5] + q3.x * C2col[6] + q3.z * C2col[7];
  A1 = q0.y * C2col[0] + q0.w * C2col[1] + q1.y * C2col[2] + q1.w * C2col[3] +
       q2.y * C2col[4] + q2.w * C2col[5] + q3.y * C2col[6] + q3.w * C2col[7];

  float acc = 0.f;
#pragma unroll
  for (int a = 0; a < NL; ++a)
    acc += (Mh[a] - ((a == 0) ? A0 : A1)) * P[a];
  acc = g8sum(acc);

  if (m == 0) fgw_s[node_loc][tg] = acc;
  __syncthreads();

  if (tid < 16) {
    const int nl2 = tid >> 3, c = tid & 7;
    const int i_out = blockIdx.x * 2 + nl2;
    float o = bias[c];
#pragma unroll
    for (int t2 = 0; t2 < TT; ++t2) o += fgw_s[nl2][t2] * W[t2 * 8 + c];
    out[i_out * 8 + c] = o;
  }
}

extern "C" void kernel_launch(void* const* d_in, const int* in_sizes, int n_in,
                              void* d_out, int out_size, void* d_ws, size_t ws_size,
                              hipStream_t stream) {
  const float* x = (const float*)d_in[0];
  const int* edge = (const int*)d_in[1];
  const float* L = (const float*)d_in[2];
  const float* TF = (const float*)d_in[3];
  const float* W = (const float*)d_in[4];
  const float* bias = (const float*)d_in[5];
  float* out = (float*)d_out;
  (void)in_sizes; (void)n_in; (void)d_ws; (void)ws_size; (void)out_size;

  fgw_dpp_kernel<<<N_NODES / 2, 256, 0, stream>>>(x, edge, L, TF, W, bias,
                                                  out);
}

// Round 11
// 742.897 us; speedup vs baseline: 3.0064x; 1.0040x over previous
//
#include <hip/hip_runtime.h>

// OT_GNN_layer — round 11: transcendental-count attack.
// N,F,T,Tn,C = 10000,128,16,8,8 ; E=160000 ; planar edge_index; hardcoded.
// Layout (validated R9/R10): wave = (node, 8-template half), lane=(t,m) owns
// the 17-row column m of template toff+t in registers.
// Changes vs R10 (dur 746us, VALUBusy 49%, trans-dominated model):
//  - Montgomery batched reciprocals: u-step 17 rcp -> 4 rcp + ~39 mul.
//  - exp2 factored: E_M[a]=exp2(-Mh*c) once per wave; 2 exp2 per outer iter
//    (17*5 -> 17+10 total). K = P * E_M * exp2((gmin+A)*c).
//  - dropped +TINY (r,r2 > 0 provably), peeled vv=1 first inner iter.
//  - C2s padded [8][9] and sc exchange padded (kills the 56/wave = 1.12M
//    8-way bank conflicts), preamble hoisted to a setup kernel via d_ws.

#define F_DIM 128
#define KN 16
#define NL 17
#define TT 16
#define TN 8
#define N_NODES 10000
#define E_EDGES 160000
#define CEXP 7.2134752044448170f  // (1/EPS)*log2(e), EPS=0.2

typedef float v2f __attribute__((ext_vector_type(2)));

template <int CTRL>
__device__ __forceinline__ float dppmov(float x) {
  return __int_as_float(__builtin_amdgcn_update_dpp(
      0, __float_as_int(x), CTRL, 0xF, 0xF, true));
}
__device__ __forceinline__ float g8sum(float x) {
  x += dppmov<0xB1>(x);   // xor 1
  x += dppmov<0x4E>(x);   // xor 2
  x += dppmov<0x141>(x);  // xor 4 (row_half_mirror)
  return x;
}
__device__ __forceinline__ float g8min(float x) {
  x = fminf(x, dppmov<0xB1>(x));
  x = fminf(x, dppmov<0x4E>(x));
  x = fminf(x, dppmov<0x141>(x));
  return x;
}

// batched reciprocal of 17 positive values: 4 rcp + ~39 mul
__device__ __forceinline__ void minv17(const float r[NL], float U[NL]) {
  {
    float p1 = r[0] * r[1], p2 = p1 * r[2], p3 = p2 * r[3];
    float R = __builtin_amdgcn_rcpf(p3);
    U[3] = R * p2; R *= r[3];
    U[2] = R * p1; R *= r[2];
    U[1] = R * r[0];
    U[0] = R * r[1];
  }
  {
    float p1 = r[4] * r[5], p2 = p1 * r[6], p3 = p2 * r[7];
    float R = __builtin_amdgcn_rcpf(p3);
    U[7] = R * p2; R *= r[7];
    U[6] = R * p1; R *= r[6];
    U[5] = R * r[4];
    U[4] = R * r[5];
  }
  {
    float p1 = r[8] * r[9], p2 = p1 * r[10], p3 = p2 * r[11];
    float R = __builtin_amdgcn_rcpf(p3);
    U[11] = R * p2; R *= r[11];
    U[10] = R * p1; R *= r[10];
    U[9] = R * r[8];
    U[8] = R * r[9];
  }
  {
    float p1 = r[12] * r[13], p2 = p1 * r[14], p3 = p2 * r[15],
          p4 = p3 * r[16];
    float R = __builtin_amdgcn_rcpf(p4);
    U[16] = R * p3; R *= r[16];
    U[15] = R * p2; R *= r[15];
    U[14] = R * p1; R *= r[14];
    U[13] = R * r[12];
    U[12] = R * r[13];
  }
}

// ---------------- setup: tfsq | cc | C2 into workspace ----------------
// ws layout (floats): tfsq[128] | cc[128] | C2[1024]
__global__ __launch_bounds__(256) void setup_kernel(
    const float* __restrict__ L, const float* __restrict__ TF,
    float* __restrict__ ws) {
  const int tid = threadIdx.x;
  if (tid < 128) {
    const int t = tid >> 3, r = tid & 7;
    float q = 0.f;
#pragma unroll
    for (int mm = 0; mm < TN; ++mm) {
      float val = 0.5f * (L[t * 64 + r * 8 + mm] + L[t * 64 + mm * 8 + r]);
      ws[256 + t * 64 + r * 8 + mm] = val;
      q += val * val;
    }
    ws[128 + tid] = 0.125f * q;
  } else {
    const int row = tid - 128;
    const float4* tf = (const float4*)(TF + (size_t)row * F_DIM);
    float s = 0.f;
#pragma unroll
    for (int c = 0; c < 32; ++c) {
      float4 v = tf[c];
      s += v.x * v.x + v.y * v.y + v.z * v.z + v.w * v.w;
    }
    ws[row] = s;
  }
}

// ---------------- main ----------------
__global__ __launch_bounds__(256) void fgw_kernel(
    const float* __restrict__ x, const int* __restrict__ edge,
    const float* __restrict__ TF, const float* __restrict__ W,
    const float* __restrict__ bias, const float* __restrict__ ws,
    float* __restrict__ out) {
  __shared__ float C2s[TT][TN][TN + 1];  // padded: kills 8-way conflicts
  __shared__ float ccs[TT * TN];
  __shared__ float tfsqs[TT * TN];
  __shared__ float2 sc[4][72];           // padded exchange (stride 9/group)
  __shared__ float fgw_s[2][TT];

  const int tid = threadIdx.x;

  // stage precomputed tables from ws
  for (int i = tid; i < 256; i += 256) {
    if (i < 128) tfsqs[i] = ws[i];
    else ccs[i - 128] = ws[i];
  }
  for (int i = tid; i < 1024; i += 256) {
    int t = i >> 6, l = (i >> 3) & 7, m = i & 7;
    C2s[t][l][m] = ws[256 + i];
  }
  __syncthreads();

  const int lane = tid & 63;
  const int wave = tid >> 6;
  const int node_loc = wave >> 1;
  const int toff = (wave & 1) * 8;
  const int node = blockIdx.x * 2 + node_loc;
  const int tl = lane >> 3, m = lane & 7;
  const int tg = toff + tl;

  const int* dst = edge + E_EDGES;
  int na[NL];
  na[0] = node;
#pragma unroll
  for (int j = 0; j < KN; ++j) na[1 + j] = dst[node * KN + j];

  // ---- xsq on lanes 0..16 ----
  float xq_h = 0.f;
  if (lane < NL) {
    const int my_row = (lane == 0) ? node : dst[node * KN + (lane - 1)];
    const float4* xr = (const float4*)(x + (size_t)my_row * F_DIM);
    v2f xq = {0.f, 0.f};
#pragma unroll
    for (int c = 0; c < 32; ++c) {
      float4 xv = xr[c];
      v2f xa = {xv.x, xv.y}, xb = {xv.z, xv.w};
      xq = xa * xa + xq;
      xq = xb * xb + xq;
    }
    xq_h = xq.x + xq.y;
  }

  // ---- dot phase (validated R10): pk_fma ----
  v2f dot2[NL];
#pragma unroll
  for (int a = 0; a < NL; ++a) dot2[a] = (v2f){0.f, 0.f};
  const float4* TFrow = (const float4*)(TF + (size_t)(tg * 8 + m) * F_DIM);
#pragma unroll 4
  for (int c = 0; c < 32; ++c) {
    float4 tf = TFrow[c];
    v2f ta = {tf.x, tf.y}, tb = {tf.z, tf.w};
#pragma unroll
    for (int a = 0; a < NL; ++a) {
      float4 xv = *(const float4*)(x + (size_t)na[a] * F_DIM + c * 4);
      v2f xa = {xv.x, xv.y}, xb = {xv.z, xv.w};
      dot2[a] = xa * ta + dot2[a];
      dot2[a] = xb * tb + dot2[a];
    }
  }

  // ---- Mh, E_M ----
  const float hw = 1.f / 17.f;
  const float tfsq_l = tfsqs[tg * 8 + m];
  const float cc_l = ccs[tg * 8 + m];
  const float base0 = 0.5f * (16.f / 17.f + cc_l);
  const float basea = 0.5f * (1.f / 17.f + cc_l);

  float Mh[NL], EM[NL];
#pragma unroll
  for (int a = 0; a < NL; ++a) {
    float xsqa = __shfl(xq_h, a, 64);
    float dh = dot2[a].x + dot2[a].y;
    Mh[a] = (xsqa + tfsq_l - 2.f * dh) * (1.f / 256.f) +
            ((a == 0) ? base0 : basea);
    EM[a] = exp2f(-Mh[a] * CEXP);
  }
  float mhmin_rest = Mh[1];
#pragma unroll
  for (int a = 2; a < NL; ++a) mhmin_rest = fminf(mhmin_rest, Mh[a]);

  float C2col[TN];
#pragma unroll
  for (int l = 0; l < TN; ++l) C2col[l] = C2s[tg][l][m];

  float PK[NL], U[NL], r[NL];
#pragma unroll
  for (int a = 0; a < NL; ++a) PK[a] = hw * 0.125f;

  float A0 = 0.f, A1 = 0.f;
#pragma unroll 1
  for (int it = 0; it < 5; ++it) {
    // ---- A = C1 P C2 via padded LDS exchange of (sP, p0) ----
    float sP = 0.f;
#pragma unroll
    for (int a = 1; a < NL; ++a) sP += PK[a];
    sc[wave][lane + tl] = make_float2(sP, PK[0]);
    const float4* q = (const float4*)&sc[wave][tl * 9];
    float4 q0 = q[0], q1 = q[1], q2 = q[2], q3 = q[3];
    A0 = q0.x * C2col[0] + q0.z * C2col[1] + q1.x * C2col[2] +
         q1.z * C2col[3] + q2.x * C2col[4] + q2.z * C2col[5] +
         q3.x * C2col[6] + q3.z * C2col[7];
    A1 = q0.y * C2col[0] + q0.w * C2col[1] + q1.y * C2col[2] +
         q1.w * C2col[3] + q2.y * C2col[4] + q2.w * C2col[5] +
         q3.y * C2col[6] + q3.w * C2col[7];

    // ---- gmin (needed to keep Sinkhorn row-sums in Montgomery-safe range)
    float gmin = fminf(mhmin_rest - A1, Mh[0] - A0);
    gmin = g8min(gmin);

    // ---- K = P * E_M * exp2((gmin + A)*c)  (2 exp2 per outer) ----
    const float EA0 = exp2f((gmin + A0) * CEXP);
    const float EA1 = exp2f((gmin + A1) * CEXP);
    PK[0] = PK[0] * EM[0] * EA0;
#pragma unroll
    for (int a = 1; a < NL; ++a) PK[a] = PK[a] * EM[a] * EA1;

    // ---- Sinkhorn: peeled si=0 (vv = 1) ----
    float vv;
    {
#pragma unroll
      for (int a = 0; a < NL; ++a) r[a] = g8sum(PK[a]);
      minv17(r, U);
      float r2a = 0.f, r2b = 0.f, r2c = 0.f, r2d = 0.f;
#pragma unroll
      for (int a = 0; a < 4; ++a) r2a = fmaf(PK[a], U[a], r2a);
#pragma unroll
      for (int a = 4; a < 8; ++a) r2b = fmaf(PK[a], U[a], r2b);
#pragma unroll
      for (int a = 8; a < 12; ++a) r2c = fmaf(PK[a], U[a], r2c);
#pragma unroll
      for (int a = 12; a < NL; ++a) r2d = fmaf(PK[a], U[a], r2d);
      vv = 2.125f * __builtin_amdgcn_rcpf((r2a + r2b) + (r2c + r2d));
    }
#pragma unroll 1
    for (int si = 1; si < 10; ++si) {
#pragma unroll
      for (int a = 0; a < NL; ++a) r[a] = g8sum(PK[a] * vv);
      minv17(r, U);
      float r2a = 0.f, r2b = 0.f, r2c = 0.f, r2d = 0.f;
#pragma unroll
      for (int a = 0; a < 4; ++a) r2a = fmaf(PK[a], U[a], r2a);
#pragma unroll
      for (int a = 4; a < 8; ++a) r2b = fmaf(PK[a], U[a], r2b);
#pragma unroll
      for (int a = 8; a < 12; ++a) r2c = fmaf(PK[a], U[a], r2c);
#pragma unroll
      for (int a = 12; a < NL; ++a) r2d = fmaf(PK[a], U[a], r2d);
      vv = 2.125f * __builtin_amdgcn_rcpf((r2a + r2b) + (r2c + r2d));
    }
    // P = U * K * (hw*vv)   (U from last u-step, vv from last v-step)
    const float pv = hw * vv;
#pragma unroll
    for (int a = 0; a < NL; ++a) PK[a] = U[a] * PK[a] * pv;
  }

  // ---- final fgw ----
  float sP = 0.f;
#pragma unroll
  for (int a = 1; a < NL; ++a) sP += PK[a];
  sc[wave][lane + tl] = make_float2(sP, PK[0]);
  const float4* q = (const float4*)&sc[wave][tl * 9];
  float4 q0 = q[0], q1 = q[1], q2 = q[2], q3 = q[3];
  A0 = q0.x * C2col[0] + q0.z * C2col[1] + q1.x * C2col[2] + q1.z * C2col[3] +
       q2.x * C2col[4] + q2.z * C2col[5] + q3.x * C2col[6] + q3.z * C2col[7];
  A1 = q0.y * C2col[0] + q0.w * C2col[1] + q1.y * C2col[2] + q1.w * C2col[3] +
       q2.y * C2col[4] + q2.w * C2col[5] + q3.y * C2col[6] + q3.w * C2col[7];

  float acc = 0.f;
#pragma unroll
  for (int a = 0; a < NL; ++a)
    acc += (Mh[a] - ((a == 0) ? A0 : A1)) * PK[a];
  acc = g8sum(acc);

  if (m == 0) fgw_s[node_loc][tg] = acc;
  __syncthreads();

  if (tid < 16) {
    const int nl2 = tid >> 3, c = tid & 7;
    const int i_out = blockIdx.x * 2 + nl2;
    float o = bias[c];
#pragma unroll
    for (int t2 = 0; t2 < TT; ++t2) o += fgw_s[nl2][t2] * W[t2 * 8 + c];
    out[i_out * 8 + c] = o;
  }
}

extern "C" void kernel_launch(void* const* d_in, const int* in_sizes, int n_in,
                              void* d_out, int out_size, void* d_ws, size_t ws_size,
                              hipStream_t stream) {
  const float* x = (const float*)d_in[0];
  const int* edge = (const int*)d_in[1];
  const float* L = (const float*)d_in[2];
  const float* TF = (const float*)d_in[3];
  const float* W = (const float*)d_in[4];
  const float* bias = (const float*)d_in[5];
  float* out = (float*)d_out;
  float* ws = (float*)d_ws;
  (void)in_sizes; (void)n_in; (void)ws_size; (void)out_size;

  setup_kernel<<<1, 256, 0, stream>>>(L, TF, ws);
  fgw_kernel<<<N_NODES / 2, 256, 0, stream>>>(x, edge, TF, W, bias, ws, out);
}

// Round 12
// 469.780 us; speedup vs baseline: 4.7543x; 1.5814x over previous
//
#include <hip/hip_runtime.h>

// OT_GNN_layer — round 12: phase-split (Mh precompute | Sinkhorn).
// N,F,T,Tn,C = 10000,128,16,8,8 ; E=160000 ; planar edge; hardcoded.
// R9-R11 plateau at ~745us across huge instruction-mix changes => per-wave
// latency-bound (occupancy & VALUBusy co-vary, dur constant). Split isolates
// the two latency sources:
//  A) mh_kernel: Mh for all (node,t,m,a) -> ws (87 MB). x rows staged once
//     per node into LDS (coalesced), TF pre-transposed (coalesced), stores
//     coalesced. Kills the 544 wave-uniform scattered loads of the fused dot.
//  B) sink_kernel: validated R11 Sinkhorn, Mh via 17 coalesced 256B loads.
// Fallback to the validated R11 fused kernel if ws_size is too small.

#define F_DIM 128
#define KN 16
#define NL 17
#define TT 16
#define TN 8
#define N_NODES 10000
#define E_EDGES 160000
#define CEXP 7.2134752044448170f  // (1/EPS)*log2(e), EPS=0.2

// ws float offsets
#define WS_TFSQ 0
#define WS_CC 128
#define WS_C2 256
#define WS_TFT 1280          // 4096 float4 = 16384 floats (byte off 5120, 16B ok)
#define WS_MH 17664          // 10000*17*128 = 21,760,000 floats
#define WS_FLOATS_NEEDED (17664 + 21760000)

typedef float v2f __attribute__((ext_vector_type(2)));

template <int CTRL>
__device__ __forceinline__ float dppmov(float x) {
  return __int_as_float(__builtin_amdgcn_update_dpp(
      0, __float_as_int(x), CTRL, 0xF, 0xF, true));
}
__device__ __forceinline__ float g8sum(float x) {
  x += dppmov<0xB1>(x);
  x += dppmov<0x4E>(x);
  x += dppmov<0x141>(x);
  return x;
}
__device__ __forceinline__ float g8min(float x) {
  x = fminf(x, dppmov<0xB1>(x));
  x = fminf(x, dppmov<0x4E>(x));
  x = fminf(x, dppmov<0x141>(x));
  return x;
}

__device__ __forceinline__ void minv17(const float r[NL], float U[NL]) {
  {
    float p1 = r[0] * r[1], p2 = p1 * r[2], p3 = p2 * r[3];
    float R = __builtin_amdgcn_rcpf(p3);
    U[3] = R * p2; R *= r[3];
    U[2] = R * p1; R *= r[2];
    U[1] = R * r[0];
    U[0] = R * r[1];
  }
  {
    float p1 = r[4] * r[5], p2 = p1 * r[6], p3 = p2 * r[7];
    float R = __builtin_amdgcn_rcpf(p3);
    U[7] = R * p2; R *= r[7];
    U[6] = R * p1; R *= r[6];
    U[5] = R * r[4];
    U[4] = R * r[5];
  }
  {
    float p1 = r[8] * r[9], p2 = p1 * r[10], p3 = p2 * r[11];
    float R = __builtin_amdgcn_rcpf(p3);
    U[11] = R * p2; R *= r[11];
    U[10] = R * p1; R *= r[10];
    U[9] = R * r[8];
    U[8] = R * r[9];
  }
  {
    float p1 = r[12] * r[13], p2 = p1 * r[14], p3 = p2 * r[15],
          p4 = p3 * r[16];
    float R = __builtin_amdgcn_rcpf(p4);
    U[16] = R * p3; R *= r[16];
    U[15] = R * p2; R *= r[15];
    U[14] = R * p1; R *= r[14];
    U[13] = R * r[12];
    U[12] = R * r[13];
  }
}

// ---------------- setup: tables + TF transpose ----------------
__global__ __launch_bounds__(256) void setup_kernel(
    const float* __restrict__ L, const float* __restrict__ TF,
    float* __restrict__ ws, int do_tft) {
  const int tid = threadIdx.x;
  if (tid < 128) {
    const int t = tid >> 3, r = tid & 7;
    float q = 0.f;
#pragma unroll
    for (int mm = 0; mm < TN; ++mm) {
      float val = 0.5f * (L[t * 64 + r * 8 + mm] + L[t * 64 + mm * 8 + r]);
      ws[WS_C2 + t * 64 + r * 8 + mm] = val;
      q += val * val;
    }
    ws[WS_CC + tid] = 0.125f * q;
  } else {
    const int row = tid - 128;
    const float4* tf = (const float4*)(TF + (size_t)row * F_DIM);
    float s = 0.f;
#pragma unroll
    for (int c = 0; c < 32; ++c) {
      float4 v = tf[c];
      s += v.x * v.x + v.y * v.y + v.z * v.z + v.w * v.w;
    }
    ws[WS_TFSQ + row] = s;
  }
  if (do_tft) {
    // TF_T[c][row] (float4 chunks): 4096 entries
    float4* tft = (float4*)(ws + WS_TFT);
    const float4* tf4 = (const float4*)TF;
    for (int i = tid; i < 4096; i += 256) {
      int row = i >> 5, c = i & 31;
      tft[c * 128 + row] = tf4[i];
    }
  }
}

// ---------------- phase A: Mh precompute ----------------
// 2 nodes per block (256 thr). Mh layout: [node][a][sub=t*8+m]
__global__ __launch_bounds__(256) void mh_kernel(
    const float* __restrict__ x, const int* __restrict__ edge,
    const float* __restrict__ ws, float* __restrict__ mh) {
  __shared__ float xls[2][NL][132];
  __shared__ float xsqs[2][NL];
  __shared__ int nas[2][NL];
  __shared__ float tfsqs[128], ccs[128];

  const int tid = threadIdx.x;
  const int node0 = blockIdx.x * 2;
  const int* dst = edge + E_EDGES;

  if (tid < 128) {
    tfsqs[tid] = ws[WS_TFSQ + tid];
    ccs[tid] = ws[WS_CC + tid];
  }
  if (tid < NL) {
    nas[0][tid] = (tid == 0) ? node0 : dst[node0 * KN + tid - 1];
  } else if (tid >= 64 && tid < 64 + NL) {
    int a = tid - 64;
    nas[1][a] = (a == 0) ? (node0 + 1) : dst[(node0 + 1) * KN + a - 1];
  }
  __syncthreads();

  // stage 2*17 rows of x, coalesced
  for (int i = tid; i < 2 * NL * 32; i += 256) {
    int nl = (i >= NL * 32) ? 1 : 0;
    int ii = i - nl * NL * 32;
    int row = ii >> 5, c4 = ii & 31;
    float4 v = ((const float4*)(x + (size_t)nas[nl][row] * F_DIM))[c4];
    *(float4*)&xls[nl][row][c4 * 4] = v;
  }
  __syncthreads();

  // xsq per row (rows padded 132 -> conflict-light)
  if (tid < NL || (tid >= 64 && tid < 64 + NL)) {
    int nl = (tid >= 64) ? 1 : 0;
    int a = (tid >= 64) ? (tid - 64) : tid;
    v2f xq = {0.f, 0.f};
#pragma unroll
    for (int c = 0; c < 32; ++c) {
      float4 xv = *(const float4*)&xls[nl][a][c * 4];
      v2f xa = {xv.x, xv.y}, xb = {xv.z, xv.w};
      xq = xa * xa + xq;
      xq = xb * xb + xq;
    }
    xsqs[nl][a] = xq.x + xq.y;
  }
  __syncthreads();

  const int nl = tid >> 7;
  const int sub = tid & 127;  // (t,m) = (sub>>3, sub&7)

  v2f dot2[NL];
#pragma unroll
  for (int a = 0; a < NL; ++a) dot2[a] = (v2f){0.f, 0.f};

  const float4* tft = (const float4*)(ws + WS_TFT);
#pragma unroll 4
  for (int c = 0; c < 32; ++c) {
    float4 tf = tft[c * 128 + sub];  // coalesced 1KB/wave
    v2f ta = {tf.x, tf.y}, tb = {tf.z, tf.w};
#pragma unroll
    for (int a = 0; a < NL; ++a) {
      float4 xv = *(const float4*)&xls[nl][a][c * 4];  // LDS broadcast
      v2f xa = {xv.x, xv.y}, xb = {xv.z, xv.w};
      dot2[a] = xa * ta + dot2[a];
      dot2[a] = xb * tb + dot2[a];
    }
  }

  const float tfsq_l = tfsqs[sub];
  const float cc_l = ccs[sub];
  const float base0 = 0.5f * (16.f / 17.f + cc_l);
  const float basea = 0.5f * (1.f / 17.f + cc_l);
  const int node = node0 + nl;

#pragma unroll
  for (int a = 0; a < NL; ++a) {
    float dh = dot2[a].x + dot2[a].y;
    float mhv = (xsqs[nl][a] + tfsq_l - 2.f * dh) * (1.f / 256.f) +
                ((a == 0) ? base0 : basea);
    mh[((size_t)node * NL + a) * 128 + sub] = mhv;  // coalesced 512B
  }
}

// ---------------- phase B: Sinkhorn (validated R11 math) ----------------
__global__ __launch_bounds__(256) void sink_kernel(
    const float* __restrict__ mh, const float* __restrict__ ws,
    const float* __restrict__ W, const float* __restrict__ bias,
    float* __restrict__ out) {
  __shared__ float C2s[TT][TN][TN + 1];
  __shared__ float2 sc[4][72];
  __shared__ float fgw_s[2][TT];

  const int tid = threadIdx.x;
  for (int i = tid; i < 1024; i += 256) {
    int t = i >> 6, l = (i >> 3) & 7, m2 = i & 7;
    C2s[t][l][m2] = ws[WS_C2 + i];
  }
  __syncthreads();

  const int lane = tid & 63;
  const int wave = tid >> 6;
  const int node_loc = wave >> 1;
  const int toff = (wave & 1) * 8;
  const int node = blockIdx.x * 2 + node_loc;
  const int tl = lane >> 3, m = lane & 7;
  const int tg = toff + tl;

  const float hw = 1.f / 17.f;

  float Mh[NL], EM[NL];
#pragma unroll
  for (int a = 0; a < NL; ++a) {
    Mh[a] = mh[((size_t)node * NL + a) * 128 + toff * 8 + lane];
    EM[a] = exp2f(-Mh[a] * CEXP);
  }
  float mhmin_rest = Mh[1];
#pragma unroll
  for (int a = 2; a < NL; ++a) mhmin_rest = fminf(mhmin_rest, Mh[a]);

  float C2col[TN];
#pragma unroll
  for (int l = 0; l < TN; ++l) C2col[l] = C2s[tg][l][m];

  float PK[NL], U[NL], r[NL];
#pragma unroll
  for (int a = 0; a < NL; ++a) PK[a] = hw * 0.125f;

  float A0 = 0.f, A1 = 0.f;
#pragma unroll 1
  for (int it = 0; it < 5; ++it) {
    float sP = 0.f;
#pragma unroll
    for (int a = 1; a < NL; ++a) sP += PK[a];
    sc[wave][lane + tl] = make_float2(sP, PK[0]);
    const float4* q = (const float4*)&sc[wave][tl * 9];
    float4 q0 = q[0], q1 = q[1], q2 = q[2], q3 = q[3];
    A0 = q0.x * C2col[0] + q0.z * C2col[1] + q1.x * C2col[2] +
         q1.z * C2col[3] + q2.x * C2col[4] + q2.z * C2col[5] +
         q3.x * C2col[6] + q3.z * C2col[7];
    A1 = q0.y * C2col[0] + q0.w * C2col[1] + q1.y * C2col[2] +
         q1.w * C2col[3] + q2.y * C2col[4] + q2.w * C2col[5] +
         q3.y * C2col[6] + q3.w * C2col[7];

    float gmin = fminf(mhmin_rest - A1, Mh[0] - A0);
    gmin = g8min(gmin);

    const float EA0 = exp2f((gmin + A0) * CEXP);
    const float EA1 = exp2f((gmin + A1) * CEXP);
    PK[0] = PK[0] * EM[0] * EA0;
#pragma unroll
    for (int a = 1; a < NL; ++a) PK[a] = PK[a] * EM[a] * EA1;

    float vv;
    {
#pragma unroll
      for (int a = 0; a < NL; ++a) r[a] = g8sum(PK[a]);
      minv17(r, U);
      float r2a = 0.f, r2b = 0.f, r2c = 0.f, r2d = 0.f;
#pragma unroll
      for (int a = 0; a < 4; ++a) r2a = fmaf(PK[a], U[a], r2a);
#pragma unroll
      for (int a = 4; a < 8; ++a) r2b = fmaf(PK[a], U[a], r2b);
#pragma unroll
      for (int a = 8; a < 12; ++a) r2c = fmaf(PK[a], U[a], r2c);
#pragma unroll
      for (int a = 12; a < NL; ++a) r2d = fmaf(PK[a], U[a], r2d);
      vv = 2.125f * __builtin_amdgcn_rcpf((r2a + r2b) + (r2c + r2d));
    }
#pragma unroll 1
    for (int si = 1; si < 10; ++si) {
#pragma unroll
      for (int a = 0; a < NL; ++a) r[a] = g8sum(PK[a] * vv);
      minv17(r, U);
      float r2a = 0.f, r2b = 0.f, r2c = 0.f, r2d = 0.f;
#pragma unroll
      for (int a = 0; a < 4; ++a) r2a = fmaf(PK[a], U[a], r2a);
#pragma unroll
      for (int a = 4; a < 8; ++a) r2b = fmaf(PK[a], U[a], r2b);
#pragma unroll
      for (int a = 8; a < 12; ++a) r2c = fmaf(PK[a], U[a], r2c);
#pragma unroll
      for (int a = 12; a < NL; ++a) r2d = fmaf(PK[a], U[a], r2d);
      vv = 2.125f * __builtin_amdgcn_rcpf((r2a + r2b) + (r2c + r2d));
    }
    const float pv = hw * vv;
#pragma unroll
    for (int a = 0; a < NL; ++a) PK[a] = U[a] * PK[a] * pv;
  }

  float sP = 0.f;
#pragma unroll
  for (int a = 1; a < NL; ++a) sP += PK[a];
  sc[wave][lane + tl] = make_float2(sP, PK[0]);
  const float4* q = (const float4*)&sc[wave][tl * 9];
  float4 q0 = q[0], q1 = q[1], q2 = q[2], q3 = q[3];
  A0 = q0.x * C2col[0] + q0.z * C2col[1] + q1.x * C2col[2] + q1.z * C2col[3] +
       q2.x * C2col[4] + q2.z * C2col[5] + q3.x * C2col[6] + q3.z * C2col[7];
  A1 = q0.y * C2col[0] + q0.w * C2col[1] + q1.y * C2col[2] + q1.w * C2col[3] +
       q2.y * C2col[4] + q2.w * C2col[5] + q3.y * C2col[6] + q3.w * C2col[7];

  float acc = 0.f;
#pragma unroll
  for (int a = 0; a < NL; ++a)
    acc += (Mh[a] - ((a == 0) ? A0 : A1)) * PK[a];
  acc = g8sum(acc);

  if (m == 0) fgw_s[node_loc][tg] = acc;
  __syncthreads();

  if (tid < 16) {
    const int nl2 = tid >> 3, c = tid & 7;
    const int i_out = blockIdx.x * 2 + nl2;
    float o = bias[c];
#pragma unroll
    for (int t2 = 0; t2 < TT; ++t2) o += fgw_s[nl2][t2] * W[t2 * 8 + c];
    out[i_out * 8 + c] = o;
  }
}

// ---------------- fallback: validated R11 fused kernel ----------------
__global__ __launch_bounds__(256) void fgw_fused_kernel(
    const float* __restrict__ x, const int* __restrict__ edge,
    const float* __restrict__ TF, const float* __restrict__ W,
    const float* __restrict__ bias, const float* __restrict__ ws,
    float* __restrict__ out) {
  __shared__ float C2s[TT][TN][TN + 1];
  __shared__ float ccs[TT * TN];
  __shared__ float tfsqs[TT * TN];
  __shared__ float2 sc[4][72];
  __shared__ float fgw_s[2][TT];

  const int tid = threadIdx.x;
  for (int i = tid; i < 256; i += 256) {
    if (i < 128) tfsqs[i] = ws[i];
    else ccs[i - 128] = ws[i];
  }
  for (int i = tid; i < 1024; i += 256) {
    int t = i >> 6, l = (i >> 3) & 7, m2 = i & 7;
    C2s[t][l][m2] = ws[WS_C2 + i];
  }
  __syncthreads();

  const int lane = tid & 63;
  const int wave = tid >> 6;
  const int node_loc = wave >> 1;
  const int toff = (wave & 1) * 8;
  const int node = blockIdx.x * 2 + node_loc;
  const int tl = lane >> 3, m = lane & 7;
  const int tg = toff + tl;

  const int* dst = edge + E_EDGES;
  int na[NL];
  na[0] = node;
#pragma unroll
  for (int j = 0; j < KN; ++j) na[1 + j] = dst[node * KN + j];

  float xq_h = 0.f;
  if (lane < NL) {
    const int my_row = (lane == 0) ? node : dst[node * KN + (lane - 1)];
    const float4* xr = (const float4*)(x + (size_t)my_row * F_DIM);
    v2f xq = {0.f, 0.f};
#pragma unroll
    for (int c = 0; c < 32; ++c) {
      float4 xv = xr[c];
      v2f xa = {xv.x, xv.y}, xb = {xv.z, xv.w};
      xq = xa * xa + xq;
      xq = xb * xb + xq;
    }
    xq_h = xq.x + xq.y;
  }

  v2f dot2[NL];
#pragma unroll
  for (int a = 0; a < NL; ++a) dot2[a] = (v2f){0.f, 0.f};
  const float4* TFrow = (const float4*)(TF + (size_t)(tg * 8 + m) * F_DIM);
#pragma unroll 4
  for (int c = 0; c < 32; ++c) {
    float4 tf = TFrow[c];
    v2f ta = {tf.x, tf.y}, tb = {tf.z, tf.w};
#pragma unroll
    for (int a = 0; a < NL; ++a) {
      float4 xv = *(const float4*)(x + (size_t)na[a] * F_DIM + c * 4);
      v2f xa = {xv.x, xv.y}, xb = {xv.z, xv.w};
      dot2[a] = xa * ta + dot2[a];
      dot2[a] = xb * tb + dot2[a];
    }
  }

  const float hw = 1.f / 17.f;
  const float tfsq_l = tfsqs[tg * 8 + m];
  const float cc_l = ccs[tg * 8 + m];
  const float base0 = 0.5f * (16.f / 17.f + cc_l);
  const float basea = 0.5f * (1.f / 17.f + cc_l);

  float Mh[NL], EM[NL];
#pragma unroll
  for (int a = 0; a < NL; ++a) {
    float xsqa = __shfl(xq_h, a, 64);
    float dh = dot2[a].x + dot2[a].y;
    Mh[a] = (xsqa + tfsq_l - 2.f * dh) * (1.f / 256.f) +
            ((a == 0) ? base0 : basea);
    EM[a] = exp2f(-Mh[a] * CEXP);
  }
  float mhmin_rest = Mh[1];
#pragma unroll
  for (int a = 2; a < NL; ++a) mhmin_rest = fminf(mhmin_rest, Mh[a]);

  float C2col[TN];
#pragma unroll
  for (int l = 0; l < TN; ++l) C2col[l] = C2s[tg][l][m];

  float PK[NL], U[NL], r[NL];
#pragma unroll
  for (int a = 0; a < NL; ++a) PK[a] = hw * 0.125f;

  float A0 = 0.f, A1 = 0.f;
#pragma unroll 1
  for (int it = 0; it < 5; ++it) {
    float sP = 0.f;
#pragma unroll
    for (int a = 1; a < NL; ++a) sP += PK[a];
    sc[wave][lane + tl] = make_float2(sP, PK[0]);
    const float4* q = (const float4*)&sc[wave][tl * 9];
    float4 q0 = q[0], q1 = q[1], q2 = q[2], q3 = q[3];
    A0 = q0.x * C2col[0] + q0.z * C2col[1] + q1.x * C2col[2] +
         q1.z * C2col[3] + q2.x * C2col[4] + q2.z * C2col[5] +
         q3.x * C2col[6] + q3.z * C2col[7];
    A1 = q0.y * C2col[0] + q0.w * C2col[1] + q1.y * C2col[2] +
         q1.w * C2col[3] + q2.y * C2col[4] + q2.w * C2col[5] +
         q3.y * C2col[6] + q3.w * C2col[7];

    float gmin = fminf(mhmin_rest - A1, Mh[0] - A0);
    gmin = g8min(gmin);

    const float EA0 = exp2f((gmin + A0) * CEXP);
    const float EA1 = exp2f((gmin + A1) * CEXP);
    PK[0] = PK[0] * EM[0] * EA0;
#pragma unroll
    for (int a = 1; a < NL; ++a) PK[a] = PK[a] * EM[a] * EA1;

    float vv;
    {
#pragma unroll
      for (int a = 0; a < NL; ++a) r[a] = g8sum(PK[a]);
      minv17(r, U);
      float r2a = 0.f, r2b = 0.f, r2c = 0.f, r2d = 0.f;
#pragma unroll
      for (int a = 0; a < 4; ++a) r2a = fmaf(PK[a], U[a], r2a);
#pragma unroll
      for (int a = 4; a < 8; ++a) r2b = fmaf(PK[a], U[a], r2b);
#pragma unroll
      for (int a = 8; a < 12; ++a) r2c = fmaf(PK[a], U[a], r2c);
#pragma unroll
      for (int a = 12; a < NL; ++a) r2d = fmaf(PK[a], U[a], r2d);
      vv = 2.125f * __builtin_amdgcn_rcpf((r2a + r2b) + (r2c + r2d));
    }
#pragma unroll 1
    for (int si = 1; si < 10; ++si) {
#pragma unroll
      for (int a = 0; a < NL; ++a) r[a] = g8sum(PK[a] * vv);
      minv17(r, U);
      float r2a = 0.f, r2b = 0.f, r2c = 0.f, r2d = 0.f;
#pragma unroll
      for (int a = 0; a < 4; ++a) r2a = fmaf(PK[a], U[a], r2a);
#pragma unroll
      for (int a = 4; a < 8; ++a) r2b = fmaf(PK[a], U[a], r2b);
#pragma unroll
      for (int a = 8; a < 12; ++a) r2c = fmaf(PK[a], U[a], r2c);
#pragma unroll
      for (int a = 12; a < NL; ++a) r2d = fmaf(PK[a], U[a], r2d);
      vv = 2.125f * __builtin_amdgcn_rcpf((r2a + r2b) + (r2c + r2d));
    }
    const float pv = hw * vv;
#pragma unroll
    for (int a = 0; a < NL; ++a) PK[a] = U[a] * PK[a] * pv;
  }

  float sP = 0.f;
#pragma unroll
  for (int a = 1; a < NL; ++a) sP += PK[a];
  sc[wave][lane + tl] = make_float2(sP, PK[0]);
  const float4* q = (const float4*)&sc[wave][tl * 9];
  float4 q0 = q[0], q1 = q[1], q2 = q[2], q3 = q[3];
  A0 = q0.x * C2col[0] + q0.z * C2col[1] + q1.x * C2col[2] + q1.z * C2col[3] +
       q2.x * C2col[4] + q2.z * C2col[5] + q3.x * C2col[6] + q3.z * C2col[7];
  A1 = q0.y * C2col[0] + q0.w * C2col[1] + q1.y * C2col[2] + q1.w * C2col[3] +
       q2.y * C2col[4] + q2.w * C2col[5] + q3.y * C2col[6] + q3.w * C2col[7];

  float acc = 0.f;
#pragma unroll
  for (int a = 0; a < NL; ++a)
    acc += (Mh[a] - ((a == 0) ? A0 : A1)) * PK[a];
  acc = g8sum(acc);

  if (m == 0) fgw_s[node_loc][tg] = acc;
  __syncthreads();

  if (tid < 16) {
    const int nl2 = tid >> 3, c = tid & 7;
    const int i_out = blockIdx.x * 2 + nl2;
    float o = bias[c];
#pragma unroll
    for (int t2 = 0; t2 < TT; ++t2) o += fgw_s[nl2][t2] * W[t2 * 8 + c];
    out[i_out * 8 + c] = o;
  }
}

extern "C" void kernel_launch(void* const* d_in, const int* in_sizes, int n_in,
                              void* d_out, int out_size, void* d_ws, size_t ws_size,
                              hipStream_t stream) {
  const float* x = (const float*)d_in[0];
  const int* edge = (const int*)d_in[1];
  const float* L = (const float*)d_in[2];
  const float* TF = (const float*)d_in[3];
  const float* W = (const float*)d_in[4];
  const float* bias = (const float*)d_in[5];
  float* out = (float*)d_out;
  float* ws = (float*)d_ws;
  (void)in_sizes; (void)n_in; (void)out_size;

  const bool split = ws_size >= (size_t)WS_FLOATS_NEEDED * 4;
  setup_kernel<<<1, 256, 0, stream>>>(L, TF, ws, split ? 1 : 0);
  if (split) {
    float* mh = ws + WS_MH;
    mh_kernel<<<N_NODES / 2, 256, 0, stream>>>(x, edge, ws, mh);
    sink_kernel<<<N_NODES / 2, 256, 0, stream>>>(mh, ws, W, bias, out);
  } else {
    fgw_fused_kernel<<<N_NODES / 2, 256, 0, stream>>>(x, edge, TF, W, bias,
                                                      ws, out);
  }
}

// Round 13
// 333.531 us; speedup vs baseline: 6.6964x; 1.4085x over previous
//
#include <hip/hip_runtime.h>

// OT_GNN_layer — round 13: instruction-count attack on both split phases.
// N,F,T,Tn,C = 10000,128,16,8,8 ; E=160000 ; planar edge; hardcoded.
//  sink: 4 lanes per (node,t) [quad-aligned], lane owns 2 plan columns packed
//        in v2f. u-step: pk_mul + 2 quad-DPP stages per row; v-step lane-local
//        17 pk_fma. Montgomery-17 for reciprocals. Mh recovered via log2(EM).
//  mh:   4 nodes/block, 64 thr/node, 2 subs/thread (each LDS x-read feeds
//        4 pk_fma), two row passes (9+8) to cap registers.

#define F_DIM 128
#define KN 16
#define NL 17
#define TT 16
#define TN 8
#define N_NODES 10000
#define E_EDGES 160000
#define CEXP 7.2134752044448170f   // (1/EPS)*log2(e), EPS=0.2
#define ICEXP 0.138629436111989062f // 1/CEXP

// ws float offsets (layout validated R12)
#define WS_TFSQ 0
#define WS_CC 128
#define WS_C2 256
#define WS_TFT 1280
#define WS_MH 17664

typedef float v2f __attribute__((ext_vector_type(2)));

template <int CTRL>
__device__ __forceinline__ float dppmov(float x) {
  return __int_as_float(__builtin_amdgcn_update_dpp(
      0, __float_as_int(x), CTRL, 0xF, 0xF, true));
}
// sum / min across the aligned 4-lane quad (lanes t*4..t*4+3), replicated
__device__ __forceinline__ float q4sum(float x) {
  x += dppmov<0xB1>(x);   // quad_perm xor1
  x += dppmov<0x4E>(x);   // quad_perm xor2
  return x;
}
__device__ __forceinline__ float q4min(float x) {
  x = fminf(x, dppmov<0xB1>(x));
  x = fminf(x, dppmov<0x4E>(x));
  return x;
}
__device__ __forceinline__ v2f exp2v(v2f a) {
  v2f r; r.x = exp2f(a.x); r.y = exp2f(a.y); return r;
}
__device__ __forceinline__ v2f rcpv(v2f a) {
  v2f r;
  r.x = __builtin_amdgcn_rcpf(a.x);
  r.y = __builtin_amdgcn_rcpf(a.y);
  return r;
}
__device__ __forceinline__ v2f minv(v2f a, v2f b) {
  v2f r; r.x = fminf(a.x, b.x); r.y = fminf(a.y, b.y); return r;
}

// batched reciprocal of 17 positive values: 4 rcp + ~39 mul (validated R11)
__device__ __forceinline__ void minv17(const float r[NL], float U[NL]) {
  {
    float p1 = r[0] * r[1], p2 = p1 * r[2], p3 = p2 * r[3];
    float R = __builtin_amdgcn_rcpf(p3);
    U[3] = R * p2; R *= r[3];
    U[2] = R * p1; R *= r[2];
    U[1] = R * r[0];
    U[0] = R * r[1];
  }
  {
    float p1 = r[4] * r[5], p2 = p1 * r[6], p3 = p2 * r[7];
    float R = __builtin_amdgcn_rcpf(p3);
    U[7] = R * p2; R *= r[7];
    U[6] = R * p1; R *= r[6];
    U[5] = R * r[4];
    U[4] = R * r[5];
  }
  {
    float p1 = r[8] * r[9], p2 = p1 * r[10], p3 = p2 * r[11];
    float R = __builtin_amdgcn_rcpf(p3);
    U[11] = R * p2; R *= r[11];
    U[10] = R * p1; R *= r[10];
    U[9] = R * r[8];
    U[8] = R * r[9];
  }
  {
    float p1 = r[12] * r[13], p2 = p1 * r[14], p3 = p2 * r[15],
          p4 = p3 * r[16];
    float R = __builtin_amdgcn_rcpf(p4);
    U[16] = R * p3; R *= r[16];
    U[15] = R * p2; R *= r[15];
    U[14] = R * p1; R *= r[14];
    U[13] = R * r[12];
    U[12] = R * r[13];
  }
}

// ---------------- setup: tables + TF transpose (validated R12) ----------------
__global__ __launch_bounds__(256) void setup_kernel(
    const float* __restrict__ L, const float* __restrict__ TF,
    float* __restrict__ ws) {
  const int tid = threadIdx.x;
  if (tid < 128) {
    const int t = tid >> 3, r = tid & 7;
    float q = 0.f;
#pragma unroll
    for (int mm = 0; mm < TN; ++mm) {
      float val = 0.5f * (L[t * 64 + r * 8 + mm] + L[t * 64 + mm * 8 + r]);
      ws[WS_C2 + t * 64 + r * 8 + mm] = val;
      q += val * val;
    }
    ws[WS_CC + tid] = 0.125f * q;
  } else {
    const int row = tid - 128;
    const float4* tf = (const float4*)(TF + (size_t)row * F_DIM);
    float s = 0.f;
#pragma unroll
    for (int c = 0; c < 32; ++c) {
      float4 v = tf[c];
      s += v.x * v.x + v.y * v.y + v.z * v.z + v.w * v.w;
    }
    ws[WS_TFSQ + row] = s;
  }
  float4* tft = (float4*)(ws + WS_TFT);
  const float4* tf4 = (const float4*)TF;
  for (int i = tid; i < 4096; i += 256) {
    int row = i >> 5, c = i & 31;
    tft[c * 128 + row] = tf4[i];
  }
}

// ---------------- phase A: Mh precompute ----------------
// 4 nodes/block; thread (nl=tid>>6, q=tid&63) computes subs q and q+64.
template <int R0, int NR>
__device__ __forceinline__ void mh_pass(
    const float xrow[NL][132], const float* __restrict__ xsq,
    const float4* __restrict__ tft, int q, float tfsqA, float tfsqB,
    float b0A, float baA, float b0B, float baB, float* __restrict__ mhbase) {
  v2f dA[NR], dB[NR];
#pragma unroll
  for (int j = 0; j < NR; ++j) {
    dA[j] = (v2f){0.f, 0.f};
    dB[j] = (v2f){0.f, 0.f};
  }
#pragma unroll 4
  for (int c = 0; c < 32; ++c) {
    float4 tfA = tft[c * 128 + q];
    float4 tfB = tft[c * 128 + q + 64];
    v2f taA = {tfA.x, tfA.y}, tbA = {tfA.z, tfA.w};
    v2f taB = {tfB.x, tfB.y}, tbB = {tfB.z, tfB.w};
#pragma unroll
    for (int j = 0; j < NR; ++j) {
      float4 xv = *(const float4*)&xrow[R0 + j][c * 4];
      v2f xa = {xv.x, xv.y}, xb = {xv.z, xv.w};
      dA[j] = xa * taA + dA[j];
      dA[j] = xb * tbA + dA[j];
      dB[j] = xa * taB + dB[j];
      dB[j] = xb * tbB + dB[j];
    }
  }
#pragma unroll
  for (int j = 0; j < NR; ++j) {
    const int a = R0 + j;
    float dhA = dA[j].x + dA[j].y;
    float dhB = dB[j].x + dB[j].y;
    float mvA = (xsq[a] + tfsqA - 2.f * dhA) * (1.f / 256.f) +
                ((a == 0) ? b0A : baA);
    float mvB = (xsq[a] + tfsqB - 2.f * dhB) * (1.f / 256.f) +
                ((a == 0) ? b0B : baB);
    mhbase[a * 128 + q] = mvA;
    mhbase[a * 128 + q + 64] = mvB;
  }
}

__global__ __launch_bounds__(256) void mh_kernel(
    const float* __restrict__ x, const int* __restrict__ edge,
    const float* __restrict__ ws, float* __restrict__ mh) {
  __shared__ float xls[4][NL][132];
  __shared__ float xsqs[4][NL];
  __shared__ int nas[4][NL];

  const int tid = threadIdx.x;
  const int node0 = blockIdx.x * 4;
  const int* dst = edge + E_EDGES;

  if (tid < 4 * NL) {
    int nl = tid / NL, a = tid - nl * NL;
    int nd = node0 + nl;
    nas[nl][a] = (a == 0) ? nd : dst[nd * KN + a - 1];
  }
  __syncthreads();

  for (int i = tid; i < 4 * NL * 32; i += 256) {
    int nl = i / (NL * 32);
    int ii = i - nl * (NL * 32);
    int row = ii >> 5, c4 = ii & 31;
    float4 v = ((const float4*)(x + (size_t)nas[nl][row] * F_DIM))[c4];
    *(float4*)&xls[nl][row][c4 * 4] = v;
  }
  __syncthreads();

  if (tid < 4 * NL) {
    int nl = tid / NL, a = tid - nl * NL;
    v2f xq = {0.f, 0.f};
#pragma unroll
    for (int c = 0; c < 32; ++c) {
      float4 xv = *(const float4*)&xls[nl][a][c * 4];
      v2f xa = {xv.x, xv.y}, xb = {xv.z, xv.w};
      xq = xa * xa + xq;
      xq = xb * xb + xq;
    }
    xsqs[nl][a] = xq.x + xq.y;
  }
  __syncthreads();

  const int nl = tid >> 6;
  const int q = tid & 63;
  const int node = node0 + nl;
  const float4* tft = (const float4*)(ws + WS_TFT);

  const float tfsqA = ws[WS_TFSQ + q];
  const float tfsqB = ws[WS_TFSQ + q + 64];
  const float ccA = ws[WS_CC + q];
  const float ccB = ws[WS_CC + q + 64];
  const float b0A = 0.5f * (16.f / 17.f + ccA), baA = 0.5f * (1.f / 17.f + ccA);
  const float b0B = 0.5f * (16.f / 17.f + ccB), baB = 0.5f * (1.f / 17.f + ccB);

  float* mhbase = mh + (size_t)node * NL * 128;
  mh_pass<0, 9>(xls[nl], xsqs[nl], tft, q, tfsqA, tfsqB, b0A, baA, b0B, baB,
                mhbase);
  mh_pass<9, 8>(xls[nl], xsqs[nl], tft, q, tfsqA, tfsqB, b0A, baA, b0B, baB,
                mhbase);
}

// ---------------- phase B: Sinkhorn, 4 lanes per (node,t) ----------------
__global__ __launch_bounds__(256) void sink_kernel(
    const float* __restrict__ mh, const float* __restrict__ ws,
    const float* __restrict__ W, const float* __restrict__ bias,
    float* __restrict__ out) {
  __shared__ float C2s[TT * 68];     // t*68 + l*8 + m   (68: bank-spread pad)
  __shared__ float sc[4][TT * 20];   // per-wave (sP[8] | p0[8] | pad4) per t
  __shared__ float fgw_s[4][TT];

  const int tid = threadIdx.x;
  for (int i = tid; i < 1024; i += 256) {
    int t = i >> 6, rest = i & 63;
    C2s[t * 68 + rest] = ws[WS_C2 + i];
  }
  __syncthreads();

  const int lane = tid & 63;
  const int w = tid >> 6;
  const int node = blockIdx.x * 4 + w;
  const int t = lane >> 2;   // template
  const int p = lane & 3;    // column pair: m = {2p, 2p+1}

  // ---- load Mh (coalesced float2), build EM, track mins ----
  const float* mhb = mh + (size_t)node * NL * 128 + t * 8 + 2 * p;
  v2f EM2[NL], Mh02, mnr;
  {
    v2f m0 = *(const v2f*)(mhb);
    Mh02 = m0;
    EM2[0] = exp2v(-m0 * CEXP);
    v2f m1 = *(const v2f*)(mhb + 128);
    mnr = m1;
    EM2[1] = exp2v(-m1 * CEXP);
#pragma unroll
    for (int a = 2; a < NL; ++a) {
      v2f mv = *(const v2f*)(mhb + a * 128);
      mnr = minv(mnr, mv);
      EM2[a] = exp2v(-mv * CEXP);
    }
  }

  v2f PK2[NL];
#pragma unroll
  for (int a = 0; a < NL; ++a) PK2[a] = (v2f){1.f / 136.f, 1.f / 136.f};

  float r[NL], U[NL];
  float* myc = &sc[w][t * 20];
  v2f A02, A12;

#pragma unroll 1
  for (int it = 0; it < 5; ++it) {
    // ---- A-phase: exchange (sP, p0) across the 4 lanes via LDS ----
    v2f sP2 = PK2[1];
#pragma unroll
    for (int a = 2; a < NL; ++a) sP2 += PK2[a];
    *(v2f*)&myc[2 * p] = sP2;
    *(v2f*)&myc[8 + 2 * p] = PK2[0];
    float4 s01 = *(const float4*)&myc[0];
    float4 s23 = *(const float4*)&myc[4];
    float4 p01 = *(const float4*)&myc[8];
    float4 p23 = *(const float4*)&myc[12];
    {
      const float* c2b = &C2s[t * 68 + 2 * p];
      v2f c0 = *(const v2f*)(c2b), c1 = *(const v2f*)(c2b + 8),
          c2 = *(const v2f*)(c2b + 16), c3 = *(const v2f*)(c2b + 24),
          c4 = *(const v2f*)(c2b + 32), c5 = *(const v2f*)(c2b + 40),
          c6 = *(const v2f*)(c2b + 48), c7 = *(const v2f*)(c2b + 56);
      A02 = c0 * s01.x + c1 * s01.y;
      A02 += c2 * s01.z + c3 * s01.w;
      A02 += c4 * s23.x + c5 * s23.y;
      A02 += c6 * s23.z + c7 * s23.w;
      A12 = c0 * p01.x + c1 * p01.y;
      A12 += c2 * p01.z + c3 * p01.w;
      A12 += c4 * p23.x + c5 * p23.y;
      A12 += c6 * p23.z + c7 * p23.w;
    }

    // ---- gmin over (a,m) for this (node,t) ----
    v2f g0 = Mh02 - A02, g1 = mnr - A12;
    float gmin = fminf(fminf(g0.x, g0.y), fminf(g1.x, g1.y));
    gmin = q4min(gmin);

    // ---- K = P * EM * exp2((gmin+A)*c) ----
    v2f EA0 = exp2v((A02 + gmin) * CEXP);
    v2f EA1 = exp2v((A12 + gmin) * CEXP);
    PK2[0] = PK2[0] * EM2[0] * EA0;
#pragma unroll
    for (int a = 1; a < NL; ++a) PK2[a] = PK2[a] * EM2[a] * EA1;

    // ---- Sinkhorn: peeled first iter (V = 1) ----
    v2f V;
    {
#pragma unroll
      for (int a = 0; a < NL; ++a) {
        float rr = PK2[a].x + PK2[a].y;
        r[a] = q4sum(rr);
      }
      minv17(r, U);
      v2f s2 = PK2[0] * U[0];
#pragma unroll
      for (int a = 1; a < NL; ++a) s2 += PK2[a] * U[a];
      V = 2.125f * rcpv(s2);
    }
#pragma unroll 1
    for (int si = 1; si < 10; ++si) {
#pragma unroll
      for (int a = 0; a < NL; ++a) {
        v2f pr = PK2[a] * V;
        r[a] = q4sum(pr.x + pr.y);
      }
      minv17(r, U);
      v2f s2 = PK2[0] * U[0];
#pragma unroll
      for (int a = 1; a < NL; ++a) s2 += PK2[a] * U[a];
      V = 2.125f * rcpv(s2);
    }
    const v2f hV = V * (1.f / 17.f);
#pragma unroll
    for (int a = 0; a < NL; ++a) PK2[a] = PK2[a] * U[a] * hV;
  }

  // ---- final fgw: A-phase on final P, then sum (Mh - A).*P ----
  {
    v2f sP2 = PK2[1];
#pragma unroll
    for (int a = 2; a < NL; ++a) sP2 += PK2[a];
    *(v2f*)&myc[2 * p] = sP2;
    *(v2f*)&myc[8 + 2 * p] = PK2[0];
    float4 s01 = *(const float4*)&myc[0];
    float4 s23 = *(const float4*)&myc[4];
    float4 p01 = *(const float4*)&myc[8];
    float4 p23 = *(const float4*)&myc[12];
    const float* c2b = &C2s[t * 68 + 2 * p];
    v2f c0 = *(const v2f*)(c2b), c1 = *(const v2f*)(c2b + 8),
        c2 = *(const v2f*)(c2b + 16), c3 = *(const v2f*)(c2b + 24),
        c4 = *(const v2f*)(c2b + 32), c5 = *(const v2f*)(c2b + 40),
        c6 = *(const v2f*)(c2b + 48), c7 = *(const v2f*)(c2b + 56);
    A02 = c0 * s01.x + c1 * s01.y;
    A02 += c2 * s01.z + c3 * s01.w;
    A02 += c4 * s23.x + c5 * s23.y;
    A02 += c6 * s23.z + c7 * s23.w;
    A12 = c0 * p01.x + c1 * p01.y;
    A12 += c2 * p01.z + c3 * p01.w;
    A12 += c4 * p23.x + c5 * p23.y;
    A12 += c6 * p23.z + c7 * p23.w;
  }
  v2f acc2 = {0.f, 0.f};
#pragma unroll
  for (int a = 0; a < NL; ++a) {
    v2f mh2;
    mh2.x = -__log2f(EM2[a].x) * ICEXP;
    mh2.y = -__log2f(EM2[a].y) * ICEXP;
    acc2 += (mh2 - ((a == 0) ? A02 : A12)) * PK2[a];
  }
  float acc = q4sum(acc2.x + acc2.y);  // fgw(node,t), replicated in quad

  if (p == 0) fgw_s[w][t] = acc;
  // intra-wave LDS RAW: compiler orders with lgkmcnt; no barrier needed
  if (lane < 8) {
    float o = bias[lane];
#pragma unroll
    for (int t2 = 0; t2 < TT; ++t2) o += fgw_s[w][t2] * W[t2 * 8 + lane];
    out[node * 8 + lane] = o;
  }
}

extern "C" void kernel_launch(void* const* d_in, const int* in_sizes, int n_in,
                              void* d_out, int out_size, void* d_ws, size_t ws_size,
                              hipStream_t stream) {
  const float* x = (const float*)d_in[0];
  const int* edge = (const int*)d_in[1];
  const float* L = (const float*)d_in[2];
  const float* TF = (const float*)d_in[3];
  const float* W = (const float*)d_in[4];
  const float* bias = (const float*)d_in[5];
  float* out = (float*)d_out;
  float* ws = (float*)d_ws;
  (void)in_sizes; (void)n_in; (void)ws_size; (void)out_size;

  float* mh = ws + WS_MH;
  setup_kernel<<<1, 256, 0, stream>>>(L, TF, ws);
  mh_kernel<<<N_NODES / 4, 256, 0, stream>>>(x, edge, ws, mh);
  sink_kernel<<<N_NODES / 4, 256, 0, stream>>>(mh, ws, W, bias, out);
}